// Round 4
// baseline (242.778 us; speedup 1.0000x reference)
//
#include <hip/hip_runtime.h>

#define N_ROWS 65536
#define NE 1024
#define ED 64
#define NCH 4
#define CHJ 256   // NE / NCH

static const size_t OFF_ZQ = 1;
static const size_t OFF_ME = 1 + 4194304;
static const size_t OFF_IDX = OFF_ME + (size_t)N_ROWS * NE;
#define ME_FLOATS ((size_t)N_ROWS * NE)   // 67108864
#define NBLK_ZQ 16384

// ---- e2[j] = numpy pairwise sum of cb[j]*cb[j] (bit-exact emulation) ----
__global__ void k_e2(const float* __restrict__ cb, float* __restrict__ e2) {
  const int j = blockIdx.x * 64 + threadIdx.x;
  if (j >= NE) return;
  const float* __restrict__ e = cb + (size_t)j * ED;
  float r[8];
  #pragma unroll
  for (int i = 0; i < 8; ++i) {
    float v = e[i];
    float q = v * v;
    asm volatile("" : "+v"(q));        // block FMA contraction (numpy rounds the mul)
    r[i] = q;
  }
  #pragma unroll
  for (int k = 1; k < 8; ++k) {
    #pragma unroll
    for (int i = 0; i < 8; ++i) {
      float v = e[8 * k + i];
      float q = v * v;
      asm volatile("" : "+v"(q));
      r[i] += q;
    }
  }
  e2[j] = ((r[0] + r[1]) + (r[2] + r[3])) + ((r[4] + r[5]) + (r[6] + r[7]));
}

// ---- distances + first-index argmin, bit-exact numpy/BLAS emulation ----
// 2-way j-unroll: two independent sequential FMA chains hide the 4-cyc
// dependent-FMA latency at 2-cyc issue; each chain is bit-identical to the
// single-chain version. launch_bounds(...,1): grid is only 1024 blocks, so
// don't let the allocator evict zr[64] from VGPRs.
__global__ __launch_bounds__(256, 1) void k_dist(const float* __restrict__ z,
    const float* __restrict__ cb, const float* __restrict__ e2,
    float* __restrict__ idxf) {
  __shared__ float s_d[NCH][64];
  __shared__ int   s_i[NCH][64];
  const int lane = threadIdx.x & 63;
  const int wv   = threadIdx.x >> 6;           // chunk id 0..3
  const int n    = blockIdx.x * 64 + lane;
  const int b = n >> 10, hw = n & 1023;
  const float* __restrict__ zp = z + (size_t)b * 65536 + hw;
  float zr[ED];
  #pragma unroll
  for (int d = 0; d < ED; ++d) zr[d] = zp[(size_t)d << 10];

  // z2 = numpy pairwise sum of zr*zr
  float r[8];
  #pragma unroll
  for (int i = 0; i < 8; ++i) {
    float q = zr[i] * zr[i];
    asm volatile("" : "+v"(q));
    r[i] = q;
  }
  #pragma unroll
  for (int k = 1; k < 8; ++k) {
    #pragma unroll
    for (int i = 0; i < 8; ++i) {
      float q = zr[8 * k + i] * zr[8 * k + i];
      asm volatile("" : "+v"(q));
      r[i] += q;
    }
  }
  const float z2 = ((r[0] + r[1]) + (r[2] + r[3])) + ((r[4] + r[5]) + (r[6] + r[7]));

  float best = 1e30f;
  int bidx = 0;
  const int j0 = wv * CHJ;
  for (int jj = 0; jj < CHJ; jj += 2) {
    const int ja = j0 + jj;
    const int jb = ja + 1;
    const int jua = __builtin_amdgcn_readfirstlane(ja);   // scalarize codebook addr
    const int jub = jua + 1;
    const float* __restrict__ ea = cb + (size_t)jua * ED;
    const float* __restrict__ eb = cb + (size_t)jub * ED;
    float aa = 0.0f, ab = 0.0f;
    #pragma unroll
    for (int k = 0; k < ED; ++k) {
      aa = fmaf(zr[k], ea[k], aa);   // BLAS: sequential f32 FMA chain (bit-exact)
      ab = fmaf(zr[k], eb[k], ab);   // independent chain -> latency hiding
    }
    const float da = (z2 + e2[jua]) - 2.0f * aa;
    const float db = (z2 + e2[jub]) - 2.0f * ab;
    if (da < best) { best = da; bidx = ja; }   // strict < == first-index argmin
    if (db < best) { best = db; bidx = jb; }
  }
  s_d[wv][lane] = best;
  s_i[wv][lane] = bidx;
  __syncthreads();
  if (wv == 0) {
    float bb = s_d[0][lane];
    int   bi = s_i[0][lane];
    #pragma unroll
    for (int c = 1; c < NCH; ++c) {
      const float dd = s_d[c][lane];
      if (dd < bb) { bb = dd; bi = s_i[c][lane]; }  // ascending chunks => lowest index on tie
    }
    idxf[n] = (float)bi;
  }
}

// ---- z_q gather + per-block loss partial (NO global atomics) ----
__global__ __launch_bounds__(256) void k_zq(const float* __restrict__ z,
    const float* __restrict__ cb, const float* __restrict__ idxf,
    float* __restrict__ zq, float* __restrict__ partial) {
  const int o = blockIdx.x * 256 + threadIdx.x;   // < 4194304
  const int b = o >> 16;
  const int d = (o >> 10) & 63;
  const int hw = o & 1023;
  const int n = (b << 10) + hw;
  const int idx = (int)idxf[n];
  const float v = cb[(size_t)idx * ED + d];
  zq[o] = v;
  const float diff = z[o] - v;
  float s = diff * diff;
  #pragma unroll
  for (int off = 32; off > 0; off >>= 1) s += __shfl_xor(s, off, 64);
  __shared__ float sh[4];
  if ((threadIdx.x & 63) == 0) sh[threadIdx.x >> 6] = s;
  __syncthreads();
  if (threadIdx.x == 0)
    partial[blockIdx.x] = (sh[0] + sh[1]) + (sh[2] + sh[3]);
}

__global__ void k_loss(const float* __restrict__ partial, float* __restrict__ out0) {
  const int t = threadIdx.x;  // 256 threads
  double s = 0.0;
  #pragma unroll
  for (int k = 0; k < NBLK_ZQ / 256; ++k) s += (double)partial[t + (k << 8)];
  #pragma unroll
  for (int off = 32; off > 0; off >>= 1) s += __shfl_xor(s, off, 64);
  __shared__ double sh[4];
  if ((t & 63) == 0) sh[t >> 6] = s;
  __syncthreads();
  if (t == 0)
    out0[0] = (float)(1.25 * ((sh[0] + sh[1]) + (sh[2] + sh[3])) / 4194304.0);
}

// ---- zero-fill the one-hot region with float4 stores ----
__global__ __launch_bounds__(256) void k_fill(float* __restrict__ me) {
  // me byte address is ODD*4 => me+3 is 16B-aligned.
  const size_t n4 = (ME_FLOATS - 3) >> 2;          // # of float4 slots from me+3
  float4* __restrict__ p4 = reinterpret_cast<float4*>(me + 3);
  const size_t stride = (size_t)gridDim.x * blockDim.x;
  const float4 zero4 = make_float4(0.f, 0.f, 0.f, 0.f);
  for (size_t i = blockIdx.x * (size_t)blockDim.x + threadIdx.x; i < n4; i += stride)
    p4[i] = zero4;
  if (blockIdx.x == 0 && threadIdx.x == 0) {
    me[0] = 0.f; me[1] = 0.f; me[2] = 0.f;
    me[ME_FLOATS - 1] = 0.f;
  }
}

__global__ void k_scatter(const float* __restrict__ idxf, float* __restrict__ me) {
  const int n = blockIdx.x * 256 + threadIdx.x;
  const int idx = (int)idxf[n];
  me[(size_t)n * NE + idx] = 1.0f;
}

extern "C" void kernel_launch(void* const* d_in, const int* in_sizes, int n_in,
                              void* d_out, int out_size, void* d_ws, size_t ws_size,
                              hipStream_t stream) {
  const float* z  = (const float*)d_in[0];
  const float* cb = (const float*)d_in[1];
  float* out  = (float*)d_out;
  float* zq   = out + OFF_ZQ;
  float* me   = out + OFF_ME;
  float* idxf = out + OFF_IDX;
  float* e2 = (float*)((char*)d_ws + 16);
  float* partial = me;   // staged in the one-hot region, consumed by k_loss before k_fill

  k_e2<<<16, 64, 0, stream>>>(cb, e2);
  k_dist<<<N_ROWS / 64, 256, 0, stream>>>(z, cb, e2, idxf);
  k_zq<<<NBLK_ZQ, 256, 0, stream>>>(z, cb, idxf, zq, partial);
  k_loss<<<1, 256, 0, stream>>>(partial, out);
  k_fill<<<2048, 256, 0, stream>>>(me);
  k_scatter<<<N_ROWS / 256, 256, 0, stream>>>(idxf, me);
}

// Round 5
// 224.946 us; speedup vs baseline: 1.0793x; 1.0793x over previous
//
#include <hip/hip_runtime.h>

#define N_ROWS 65536
#define NE 1024
#define ED 64

static const size_t OFF_ZQ = 1;
static const size_t OFF_ME = 1 + 4194304;
static const size_t OFF_IDX = OFF_ME + (size_t)N_ROWS * NE;
#define ME_FLOATS ((size_t)N_ROWS * NE)   // 67108864
#define NBLK_ZQ 16384

// scratch layout inside the one-hot region, from base = me+3 (16B aligned).
// All consumed before k_fill zeroes the region.
#define SC_PARTIAL 0          // [16384]
#define SC_Z2      16384      // [65536]
#define SC_CBT     81920      // [65536]  cbT[k][j], 64x1024
#define SC_E2      147456     // [1024]

// ---- one-time transpose cb[j][k] -> cbT[k][j] ----
__global__ void k_tr(const float* __restrict__ cb, float* __restrict__ cbT) {
  const int t = blockIdx.x * 256 + threadIdx.x;   // 0..16383
  const int j = t >> 4, k4 = (t & 15) << 2;
  const float4 v = *reinterpret_cast<const float4*>(cb + j * 64 + k4);
  cbT[(k4 + 0) * 1024 + j] = v.x;
  cbT[(k4 + 1) * 1024 + j] = v.y;
  cbT[(k4 + 2) * 1024 + j] = v.z;
  cbT[(k4 + 3) * 1024 + j] = v.w;
}

// ---- e2[j] = numpy pairwise sum of cb[j]*cb[j] (bit-exact emulation) ----
__global__ void k_e2(const float* __restrict__ cb, float* __restrict__ e2) {
  const int j = blockIdx.x * 64 + threadIdx.x;
  if (j >= NE) return;
  const float* __restrict__ e = cb + (size_t)j * ED;
  float r[8];
  #pragma unroll
  for (int i = 0; i < 8; ++i) {
    float v = e[i];
    float q = v * v;
    asm volatile("" : "+v"(q));        // block FMA contraction (numpy rounds the mul)
    r[i] = q;
  }
  #pragma unroll
  for (int k = 1; k < 8; ++k) {
    #pragma unroll
    for (int i = 0; i < 8; ++i) {
      float v = e[8 * k + i];
      float q = v * v;
      asm volatile("" : "+v"(q));
      r[i] += q;
    }
  }
  e2[j] = ((r[0] + r[1]) + (r[2] + r[3])) + ((r[4] + r[5]) + (r[6] + r[7]));
}

// ---- z2[n] = numpy pairwise sum of z-row squares (bit-exact emulation) ----
__global__ void k_z2(const float* __restrict__ z, float* __restrict__ z2) {
  const int n = blockIdx.x * 256 + threadIdx.x;
  const int b = n >> 10, hw = n & 1023;
  const float* __restrict__ zp = z + (size_t)b * 65536 + hw;
  float r[8];
  #pragma unroll
  for (int i = 0; i < 8; ++i) {
    const float v = zp[(size_t)i << 10];
    float q = v * v;
    asm volatile("" : "+v"(q));
    r[i] = q;
  }
  #pragma unroll
  for (int k = 1; k < 8; ++k) {
    #pragma unroll
    for (int i = 0; i < 8; ++i) {
      const float v = zp[(size_t)(8 * k + i) << 10];
      float q = v * v;
      asm volatile("" : "+v"(q));
      r[i] += q;
    }
  }
  z2[n] = ((r[0] + r[1]) + (r[2] + r[3])) + ((r[4] + r[5]) + (r[6] + r[7]));
}

// ---- register-tiled f32 "GEMM" + fused first-index argmin ----
// Block: 256 thr = 4 waves (2 row-halves x 2 col-halves), tile 64 rows x 64 cols,
// K=64. Per thread 4x4 acc; each acc[m][n] is ONE sequential f32 FMA chain over
// k=0..63 (bit-exact BLAS emulation). Tie-aware lexicographic (v, idx) min ==
// numpy first-index argmin, order-independent.
__global__ __launch_bounds__(256) void k_dist(const float* __restrict__ z,
    const float* __restrict__ cbT, const float* __restrict__ e2,
    const float* __restrict__ z2, float* __restrict__ idxf) {
  __shared__ float lz[64][64];    // [k][row]
  __shared__ float lcb[64][64];   // [k][col]
  __shared__ float s_v[2][64];
  __shared__ int   s_ix[2][64];
  const int t = threadIdx.x;
  const int w = t >> 6, lane = t & 63;
  const int wr = w & 1, wc = w >> 1;
  const int lr = lane >> 3, lcn = lane & 7;
  const int row0 = blockIdx.x * 64;
  const int b = row0 >> 10;
  const int hw0 = row0 & 1023;
  const int rbase = wr * 32 + lr * 4;
  const int cbase = wc * 32 + lcn * 4;

  // stage z tile: lz[d][r] <- z[b][d][hw0+r], coalesced float4
  const float* __restrict__ zbase = z + (size_t)b * 65536 + hw0;
  #pragma unroll
  for (int rep = 0; rep < 4; ++rep) {
    const int idx = rep * 256 + t;            // 0..1023
    const int d = idx >> 4, r4 = (idx & 15) << 2;
    const float4 v = *reinterpret_cast<const float4*>(zbase + d * 1024 + r4);
    *reinterpret_cast<float4*>(&lz[d][r4]) = v;
  }

  float z2r[4];
  #pragma unroll
  for (int m = 0; m < 4; ++m) z2r[m] = z2[row0 + rbase + m];

  float bv[4]; int bi[4];
  #pragma unroll
  for (int m = 0; m < 4; ++m) { bv[m] = 1e30f; bi[m] = 0; }

  for (int jb = 0; jb < 16; ++jb) {
    __syncthreads();   // protect lcb from previous readers (and publish lz on jb=0)
    #pragma unroll
    for (int rep = 0; rep < 4; ++rep) {
      const int idx = rep * 256 + t;
      const int d = idx >> 4, c4 = (idx & 15) << 2;
      const float4 v = *reinterpret_cast<const float4*>(cbT + d * 1024 + jb * 64 + c4);
      *reinterpret_cast<float4*>(&lcb[d][c4]) = v;
    }
    __syncthreads();

    float acc[4][4];
    #pragma unroll
    for (int m = 0; m < 4; ++m)
      #pragma unroll
      for (int n = 0; n < 4; ++n) acc[m][n] = 0.0f;

    #pragma unroll 8
    for (int k = 0; k < 64; ++k) {
      const float4 za = *reinterpret_cast<const float4*>(&lz[k][rbase]);
      const float4 ca = *reinterpret_cast<const float4*>(&lcb[k][cbase]);
      const float zv[4] = {za.x, za.y, za.z, za.w};
      const float cv[4] = {ca.x, ca.y, ca.z, ca.w};
      #pragma unroll
      for (int m = 0; m < 4; ++m)
        #pragma unroll
        for (int n = 0; n < 4; ++n)
          acc[m][n] = fmaf(zv[m], cv[n], acc[m][n]);   // sequential chain in k
    }

    // fused epilogue: d = fl(fl(z2+e2) - 2*dot), first-index argmin
    float e2r[4];
    #pragma unroll
    for (int n = 0; n < 4; ++n) e2r[n] = e2[jb * 64 + cbase + n];
    #pragma unroll
    for (int m = 0; m < 4; ++m) {
      #pragma unroll
      for (int n = 0; n < 4; ++n) {   // ascending j within thread
        const float dd = (z2r[m] + e2r[n]) - 2.0f * acc[m][n];
        const int j = jb * 64 + cbase + n;
        if (dd < bv[m]) { bv[m] = dd; bi[m] = j; }
      }
    }
  }

  // tie-aware reduce across lcn lanes (butterfly over lane bits 0..2)
  #pragma unroll
  for (int off = 1; off < 8; off <<= 1) {
    #pragma unroll
    for (int m = 0; m < 4; ++m) {
      const float ov = __shfl_xor(bv[m], off, 64);
      const int oi = __shfl_xor(bi[m], off, 64);
      if (ov < bv[m] || (ov == bv[m] && oi < bi[m])) { bv[m] = ov; bi[m] = oi; }
    }
  }
  if (lcn == 0) {
    #pragma unroll
    for (int m = 0; m < 4; ++m) { s_v[wc][rbase + m] = bv[m]; s_ix[wc][rbase + m] = bi[m]; }
  }
  __syncthreads();
  if (t < 64) {
    float v0 = s_v[0][t]; int i0 = s_ix[0][t];
    const float v1 = s_v[1][t]; const int i1 = s_ix[1][t];
    if (v1 < v0 || (v1 == v0 && i1 < i0)) { v0 = v1; i0 = i1; }
    idxf[row0 + t] = (float)i0;
  }
}

// ---- z_q gather + per-block loss partial (NO global atomics) ----
__global__ __launch_bounds__(256) void k_zq(const float* __restrict__ z,
    const float* __restrict__ cb, const float* __restrict__ idxf,
    float* __restrict__ zq, float* __restrict__ partial) {
  const int o = blockIdx.x * 256 + threadIdx.x;   // < 4194304
  const int b = o >> 16;
  const int d = (o >> 10) & 63;
  const int hw = o & 1023;
  const int n = (b << 10) + hw;
  const int idx = (int)idxf[n];
  const float v = cb[(size_t)idx * ED + d];
  zq[o] = v;
  const float diff = z[o] - v;
  float s = diff * diff;
  #pragma unroll
  for (int off = 32; off > 0; off >>= 1) s += __shfl_xor(s, off, 64);
  __shared__ float sh[4];
  if ((threadIdx.x & 63) == 0) sh[threadIdx.x >> 6] = s;
  __syncthreads();
  if (threadIdx.x == 0)
    partial[blockIdx.x] = (sh[0] + sh[1]) + (sh[2] + sh[3]);
}

__global__ void k_loss(const float* __restrict__ partial, float* __restrict__ out0) {
  const int t = threadIdx.x;  // 256 threads
  double s = 0.0;
  #pragma unroll
  for (int k = 0; k < NBLK_ZQ / 256; ++k) s += (double)partial[t + (k << 8)];
  #pragma unroll
  for (int off = 32; off > 0; off >>= 1) s += __shfl_xor(s, off, 64);
  __shared__ double sh[4];
  if ((t & 63) == 0) sh[t >> 6] = s;
  __syncthreads();
  if (t == 0)
    out0[0] = (float)(1.25 * ((sh[0] + sh[1]) + (sh[2] + sh[3])) / 4194304.0);
}

// ---- zero-fill the one-hot region with float4 stores ----
__global__ __launch_bounds__(256) void k_fill(float* __restrict__ me) {
  const size_t n4 = (ME_FLOATS - 3) >> 2;          // float4 slots from me+3
  float4* __restrict__ p4 = reinterpret_cast<float4*>(me + 3);
  const size_t stride = (size_t)gridDim.x * blockDim.x;
  const float4 zero4 = make_float4(0.f, 0.f, 0.f, 0.f);
  for (size_t i = blockIdx.x * (size_t)blockDim.x + threadIdx.x; i < n4; i += stride)
    p4[i] = zero4;
  if (blockIdx.x == 0 && threadIdx.x == 0) {
    me[0] = 0.f; me[1] = 0.f; me[2] = 0.f;
    me[ME_FLOATS - 1] = 0.f;
  }
}

__global__ void k_scatter(const float* __restrict__ idxf, float* __restrict__ me) {
  const int n = blockIdx.x * 256 + threadIdx.x;
  const int idx = (int)idxf[n];
  me[(size_t)n * NE + idx] = 1.0f;
}

extern "C" void kernel_launch(void* const* d_in, const int* in_sizes, int n_in,
                              void* d_out, int out_size, void* d_ws, size_t ws_size,
                              hipStream_t stream) {
  const float* z  = (const float*)d_in[0];
  const float* cb = (const float*)d_in[1];
  float* out  = (float*)d_out;
  float* zq   = out + OFF_ZQ;
  float* me   = out + OFF_ME;
  float* idxf = out + OFF_IDX;
  float* base = me + 3;                 // 16B-aligned scratch inside one-hot region
  float* partial = base + SC_PARTIAL;
  float* z2  = base + SC_Z2;
  float* cbT = base + SC_CBT;
  float* e2  = base + SC_E2;

  k_tr<<<64, 256, 0, stream>>>(cb, cbT);
  k_e2<<<16, 64, 0, stream>>>(cb, e2);
  k_z2<<<N_ROWS / 256, 256, 0, stream>>>(z, z2);
  k_dist<<<N_ROWS / 64, 256, 0, stream>>>(z, cbT, e2, z2, idxf);
  k_zq<<<NBLK_ZQ, 256, 0, stream>>>(z, cb, idxf, zq, partial);
  k_loss<<<1, 256, 0, stream>>>(partial, out);
  k_fill<<<2048, 256, 0, stream>>>(me);
  k_scatter<<<N_ROWS / 256, 256, 0, stream>>>(idxf, me);
}

// Round 6
// 212.274 us; speedup vs baseline: 1.1437x; 1.0597x over previous
//
#include <hip/hip_runtime.h>

#define N_ROWS 65536
#define NE 1024
#define ED 64

static const size_t OFF_ZQ = 1;
static const size_t OFF_ME = 1 + 4194304;
static const size_t OFF_IDX = OFF_ME + (size_t)N_ROWS * NE;
#define ME_FLOATS ((size_t)N_ROWS * NE)   // 67108864
#define NBLK_ZQ 16384

// scratch layout inside the one-hot region, from base = me+3 (16B aligned).
// All consumed before k_fill zeroes the region.
#define SC_PARTIAL 0          // [16384]
#define SC_Z2      16384      // [65536]
#define SC_CBT     81920      // [65536]  cbT[k][j], 64x1024
#define SC_E2      147456     // [1024]

// ---- one-time transpose cb[j][k] -> cbT[k][j] ----
__global__ void k_tr(const float* __restrict__ cb, float* __restrict__ cbT) {
  const int t = blockIdx.x * 256 + threadIdx.x;   // 0..16383
  const int j = t >> 4, k4 = (t & 15) << 2;
  const float4 v = *reinterpret_cast<const float4*>(cb + j * 64 + k4);
  cbT[(k4 + 0) * 1024 + j] = v.x;
  cbT[(k4 + 1) * 1024 + j] = v.y;
  cbT[(k4 + 2) * 1024 + j] = v.z;
  cbT[(k4 + 3) * 1024 + j] = v.w;
}

// ---- e2[j] = numpy pairwise sum of cb[j]*cb[j] (bit-exact emulation) ----
__global__ void k_e2(const float* __restrict__ cb, float* __restrict__ e2) {
  const int j = blockIdx.x * 64 + threadIdx.x;
  if (j >= NE) return;
  const float* __restrict__ e = cb + (size_t)j * ED;
  float r[8];
  #pragma unroll
  for (int i = 0; i < 8; ++i) {
    float v = e[i];
    float q = v * v;
    asm volatile("" : "+v"(q));        // block FMA contraction (numpy rounds the mul)
    r[i] = q;
  }
  #pragma unroll
  for (int k = 1; k < 8; ++k) {
    #pragma unroll
    for (int i = 0; i < 8; ++i) {
      float v = e[8 * k + i];
      float q = v * v;
      asm volatile("" : "+v"(q));
      r[i] += q;
    }
  }
  e2[j] = ((r[0] + r[1]) + (r[2] + r[3])) + ((r[4] + r[5]) + (r[6] + r[7]));
}

// ---- z2[n] = numpy pairwise sum of z-row squares (bit-exact emulation) ----
__global__ void k_z2(const float* __restrict__ z, float* __restrict__ z2) {
  const int n = blockIdx.x * 256 + threadIdx.x;
  const int b = n >> 10, hw = n & 1023;
  const float* __restrict__ zp = z + (size_t)b * 65536 + hw;
  float r[8];
  #pragma unroll
  for (int i = 0; i < 8; ++i) {
    const float v = zp[(size_t)i << 10];
    float q = v * v;
    asm volatile("" : "+v"(q));
    r[i] = q;
  }
  #pragma unroll
  for (int k = 1; k < 8; ++k) {
    #pragma unroll
    for (int i = 0; i < 8; ++i) {
      const float v = zp[(size_t)(8 * k + i) << 10];
      float q = v * v;
      asm volatile("" : "+v"(q));
      r[i] += q;
    }
  }
  z2[n] = ((r[0] + r[1]) + (r[2] + r[3])) + ((r[4] + r[5]) + (r[6] + r[7]));
}

// ---- register-tiled f32 "GEMM" + fused first-index argmin ----
// Block 256 thr, tile 128 rows x 128 cols, K=64, per-thread 8x8 acc.
// Thread (tr=t>>4, tc=t&15) owns rows {tr*4+m, 64+tr*4+m}, cols
// {tc*4+n, 64+tc*4+n}. Split-4 groups => all LDS reads are <=2-way bank
// aliased (free, m136) and 1 B/FMA LDS traffic (vs 2 B/FMA for 4x4, which
// was LDS-return-bound). Each acc is ONE sequential f32 FMA chain over
// k=0..63 (bit-exact BLAS emulation); ascending-j strict-< + lexicographic
// tie reduce == numpy first-index argmin. Rows are exclusive to a 16-lane
// tc-group => argmin finishes with 4 in-wave shuffles, no LDS reduce.
__global__ __launch_bounds__(256, 2) void k_dist(const float* __restrict__ z,
    const float* __restrict__ cbT, const float* __restrict__ e2,
    const float* __restrict__ z2, float* __restrict__ idxf) {
  __shared__ float lz[64][128];    // [k][row]  32 KB
  __shared__ float lcb[64][128];   // [k][col]  32 KB
  const int t = threadIdx.x;
  const int tr = t >> 4;           // 0..15
  const int tc = t & 15;           // 0..15
  const int row0 = blockIdx.x * 128;
  const int b = row0 >> 10;
  const int hw0 = row0 & 1023;
  const float* __restrict__ zbase = z + (size_t)b * 65536 + hw0;

  // stage z tile once: lz[d][r] <- z[b][d][hw0+r], coalesced float4
  #pragma unroll
  for (int rep = 0; rep < 8; ++rep) {
    const int o4 = rep * 256 + t;            // 0..2047
    const int d = o4 >> 5, r4 = (o4 & 31) << 2;
    const float4 v = *reinterpret_cast<const float4*>(zbase + d * 1024 + r4);
    *reinterpret_cast<float4*>(&lz[d][r4]) = v;
  }

  float z2r[2][4];
  #pragma unroll
  for (int mg = 0; mg < 2; ++mg) {
    const float4 v = *reinterpret_cast<const float4*>(z2 + row0 + mg * 64 + tr * 4);
    z2r[mg][0] = v.x; z2r[mg][1] = v.y; z2r[mg][2] = v.z; z2r[mg][3] = v.w;
  }

  float bv[2][4]; int bi[2][4];
  #pragma unroll
  for (int mg = 0; mg < 2; ++mg)
    #pragma unroll
    for (int m = 0; m < 4; ++m) { bv[mg][m] = 1e30f; bi[mg][m] = 0; }

  for (int jb = 0; jb < 8; ++jb) {
    __syncthreads();   // publish lz (jb=0) / protect lcb from previous readers
    #pragma unroll
    for (int rep = 0; rep < 8; ++rep) {
      const int o4 = rep * 256 + t;
      const int d = o4 >> 5, c4 = (o4 & 31) << 2;
      const float4 v = *reinterpret_cast<const float4*>(cbT + d * 1024 + jb * 128 + c4);
      *reinterpret_cast<float4*>(&lcb[d][c4]) = v;
    }
    __syncthreads();

    float acc[2][2][4][4];   // [mg][ng][m][n]
    #pragma unroll
    for (int mg = 0; mg < 2; ++mg)
      #pragma unroll
      for (int ng = 0; ng < 2; ++ng)
        #pragma unroll
        for (int m = 0; m < 4; ++m)
          #pragma unroll
          for (int n = 0; n < 4; ++n) acc[mg][ng][m][n] = 0.0f;

    #pragma unroll 4
    for (int k = 0; k < 64; ++k) {
      const float4 za0 = *reinterpret_cast<const float4*>(&lz[k][tr * 4]);
      const float4 za1 = *reinterpret_cast<const float4*>(&lz[k][64 + tr * 4]);
      const float4 ca0 = *reinterpret_cast<const float4*>(&lcb[k][tc * 4]);
      const float4 ca1 = *reinterpret_cast<const float4*>(&lcb[k][64 + tc * 4]);
      const float zv[2][4] = {{za0.x, za0.y, za0.z, za0.w},
                              {za1.x, za1.y, za1.z, za1.w}};
      const float cv[2][4] = {{ca0.x, ca0.y, ca0.z, ca0.w},
                              {ca1.x, ca1.y, ca1.z, ca1.w}};
      #pragma unroll
      for (int mg = 0; mg < 2; ++mg)
        #pragma unroll
        for (int ng = 0; ng < 2; ++ng)
          #pragma unroll
          for (int m = 0; m < 4; ++m)
            #pragma unroll
            for (int n = 0; n < 4; ++n)
              acc[mg][ng][m][n] = fmaf(zv[mg][m], cv[ng][n], acc[mg][ng][m][n]);
    }

    // fused epilogue: d = fl(fl(z2+e2) - 2*dot), ascending-j strict-< argmin
    float e2r[2][4];
    #pragma unroll
    for (int ng = 0; ng < 2; ++ng) {
      const float4 v = *reinterpret_cast<const float4*>(e2 + jb * 128 + ng * 64 + tc * 4);
      e2r[ng][0] = v.x; e2r[ng][1] = v.y; e2r[ng][2] = v.z; e2r[ng][3] = v.w;
    }
    #pragma unroll
    for (int mg = 0; mg < 2; ++mg)
      #pragma unroll
      for (int m = 0; m < 4; ++m)
        #pragma unroll
        for (int ng = 0; ng < 2; ++ng)   // ascending j: ng then n
          #pragma unroll
          for (int n = 0; n < 4; ++n) {
            const float dd = (z2r[mg][m] + e2r[ng][n]) - 2.0f * acc[mg][ng][m][n];
            const int j = jb * 128 + ng * 64 + tc * 4 + n;
            if (dd < bv[mg][m]) { bv[mg][m] = dd; bi[mg][m] = j; }
          }
  }

  // tie-aware reduce across the 16 tc lanes (in-wave butterfly, bits 0..3)
  #pragma unroll
  for (int off = 1; off < 16; off <<= 1) {
    #pragma unroll
    for (int mg = 0; mg < 2; ++mg)
      #pragma unroll
      for (int m = 0; m < 4; ++m) {
        const float ov = __shfl_xor(bv[mg][m], off, 64);
        const int oi = __shfl_xor(bi[mg][m], off, 64);
        if (ov < bv[mg][m] || (ov == bv[mg][m] && oi < bi[mg][m])) {
          bv[mg][m] = ov; bi[mg][m] = oi;
        }
      }
  }
  if (tc == 0) {
    #pragma unroll
    for (int mg = 0; mg < 2; ++mg)
      #pragma unroll
      for (int m = 0; m < 4; ++m)
        idxf[row0 + mg * 64 + tr * 4 + m] = (float)bi[mg][m];
  }
}

// ---- z_q gather + per-block loss partial (NO global atomics) ----
__global__ __launch_bounds__(256) void k_zq(const float* __restrict__ z,
    const float* __restrict__ cb, const float* __restrict__ idxf,
    float* __restrict__ zq, float* __restrict__ partial) {
  const int o = blockIdx.x * 256 + threadIdx.x;   // < 4194304
  const int b = o >> 16;
  const int d = (o >> 10) & 63;
  const int hw = o & 1023;
  const int n = (b << 10) + hw;
  const int idx = (int)idxf[n];
  const float v = cb[(size_t)idx * ED + d];
  zq[o] = v;
  const float diff = z[o] - v;
  float s = diff * diff;
  #pragma unroll
  for (int off = 32; off > 0; off >>= 1) s += __shfl_xor(s, off, 64);
  __shared__ float sh[4];
  if ((threadIdx.x & 63) == 0) sh[threadIdx.x >> 6] = s;
  __syncthreads();
  if (threadIdx.x == 0)
    partial[blockIdx.x] = (sh[0] + sh[1]) + (sh[2] + sh[3]);
}

__global__ void k_loss(const float* __restrict__ partial, float* __restrict__ out0) {
  const int t = threadIdx.x;  // 256 threads
  double s = 0.0;
  #pragma unroll
  for (int k = 0; k < NBLK_ZQ / 256; ++k) s += (double)partial[t + (k << 8)];
  #pragma unroll
  for (int off = 32; off > 0; off >>= 1) s += __shfl_xor(s, off, 64);
  __shared__ double sh[4];
  if ((t & 63) == 0) sh[t >> 6] = s;
  __syncthreads();
  if (t == 0)
    out0[0] = (float)(1.25 * ((sh[0] + sh[1]) + (sh[2] + sh[3])) / 4194304.0);
}

// ---- zero-fill the one-hot region with float4 stores ----
__global__ __launch_bounds__(256) void k_fill(float* __restrict__ me) {
  const size_t n4 = (ME_FLOATS - 3) >> 2;          // float4 slots from me+3
  float4* __restrict__ p4 = reinterpret_cast<float4*>(me + 3);
  const size_t stride = (size_t)gridDim.x * blockDim.x;
  const float4 zero4 = make_float4(0.f, 0.f, 0.f, 0.f);
  for (size_t i = blockIdx.x * (size_t)blockDim.x + threadIdx.x; i < n4; i += stride)
    p4[i] = zero4;
  if (blockIdx.x == 0 && threadIdx.x == 0) {
    me[0] = 0.f; me[1] = 0.f; me[2] = 0.f;
    me[ME_FLOATS - 1] = 0.f;
  }
}

__global__ void k_scatter(const float* __restrict__ idxf, float* __restrict__ me) {
  const int n = blockIdx.x * 256 + threadIdx.x;
  const int idx = (int)idxf[n];
  me[(size_t)n * NE + idx] = 1.0f;
}

extern "C" void kernel_launch(void* const* d_in, const int* in_sizes, int n_in,
                              void* d_out, int out_size, void* d_ws, size_t ws_size,
                              hipStream_t stream) {
  const float* z  = (const float*)d_in[0];
  const float* cb = (const float*)d_in[1];
  float* out  = (float*)d_out;
  float* zq   = out + OFF_ZQ;
  float* me   = out + OFF_ME;
  float* idxf = out + OFF_IDX;
  float* base = me + 3;                 // 16B-aligned scratch inside one-hot region
  float* partial = base + SC_PARTIAL;
  float* z2  = base + SC_Z2;
  float* cbT = base + SC_CBT;
  float* e2  = base + SC_E2;

  k_tr<<<64, 256, 0, stream>>>(cb, cbT);
  k_e2<<<16, 64, 0, stream>>>(cb, e2);
  k_z2<<<N_ROWS / 256, 256, 0, stream>>>(z, z2);
  k_dist<<<N_ROWS / 128, 256, 0, stream>>>(z, cbT, e2, z2, idxf);
  k_zq<<<NBLK_ZQ, 256, 0, stream>>>(z, cb, idxf, zq, partial);
  k_loss<<<1, 256, 0, stream>>>(partial, out);
  k_fill<<<2048, 256, 0, stream>>>(me);
  k_scatter<<<N_ROWS / 256, 256, 0, stream>>>(idxf, me);
}